// Round 10
// baseline (471.862 us; speedup 1.0000x reference)
//
#include <hip/hip_runtime.h>
#include <hip/hip_bf16.h>

// InfiniteNeuralNetwork: the scan state stays row-constant, so
//   p[j] = (1/D) * prod_{d,k} cos^2(inf_w[d,j,k])
// and each infinite layer is just tanh(x @ cls_w + cls_b + p).
// Network = 6 GEMMs [2048x2048x2048] with fused epilogues.
// R3: XOR-swizzle fixed 16-way LDS conflicts (93 -> ~41us/GEMM).
// R4: depth-3 counted-vmcnt pipeline (~35us/GEMM). 1 block/CU.
// R5: BN=64/BK=32, 512 blocks = 2/CU; tail weight transposes. 247us.
// R6: LDS-repacked 16B-store epilogue + setprio(1). 219us.
// R7/R9: one barrier per K-step (4 bufs) - neutral (221us). Not sync-bound.
// R10: LDS-port relief: 4x1 wave grid (wave tile 32x64, no cross-wave
//      fragment duplication) + B streamed global->registers (3 sets,
//      prefetch distance 2). LDS/step: 36KB -> 16KB.

#define DD 2048
#define DEPTH 9

#define BM 128
#define BN 64
#define BK 32
#define NT (DD / BK)   // 64 K-tiles
#define ABUF (BM * BK) // elements per A LDS buffer

typedef __attribute__((ext_vector_type(8))) short short8;
typedef __attribute__((ext_vector_type(4))) float f32x4;

__device__ __forceinline__ unsigned short f2bf(float f) {
  unsigned u = __float_as_uint(f);
  u += 0x7FFFu + ((u >> 16) & 1u);   // round-to-nearest-even
  return (unsigned short)(u >> 16);
}

// ---------------- fused prep kernel ----------------
// blocks [0,8192): transpose w0,w1 -> wts[0],wts[1]  (bf16 [N][K])
// blocks [8192,12288): cvt x -> bf16
// blocks [12288,12304): padd for both infinite layers
__global__ __launch_bounds__(256) void prep_kernel(
    const float* __restrict__ w0, const float* __restrict__ w1,
    unsigned short* __restrict__ wts, const float* __restrict__ x,
    unsigned short* __restrict__ xb, const float* __restrict__ infw1,
    const float* __restrict__ infw2, const float* __restrict__ clsb1,
    const float* __restrict__ clsb2, float* __restrict__ padd1,
    float* __restrict__ padd2) {
  int b = blockIdx.x;
  int tid = threadIdx.x;
  if (b < 8192) {
    __shared__ float tile[32][33];
    int z = b >> 12;              // 0: w0, 1: w1
    int t = b & 4095;
    const float* src = z ? w1 : w0;
    unsigned short* dst = wts + (size_t)z * DD * DD;
    int bx = (t & 63) * 32;       // n base
    int by = (t >> 6) * 32;       // k base
    int tx = tid & 31, ty = tid >> 5;
#pragma unroll
    for (int i = ty; i < 32; i += 8)
      tile[i][tx] = src[(size_t)(by + i) * DD + bx + tx];
    __syncthreads();
#pragma unroll
    for (int i = ty; i < 32; i += 8)
      dst[(size_t)(bx + i) * DD + by + tx] = f2bf(tile[tx][i]);
  } else if (b < 12288) {
    int i = (b - 8192) * 256 + tid;       // 1,048,576 float4 chunks
    float4 v = reinterpret_cast<const float4*>(x)[i];
    ushort4 o;
    o.x = f2bf(v.x); o.y = f2bf(v.y); o.z = f2bf(v.z); o.w = f2bf(v.w);
    reinterpret_cast<ushort4*>(xb)[i] = o;
  } else {
    int jj = (b - 12288) * 256 + tid;     // 0..4095
    int layer = jj >> 11;
    int j = jj & 2047;
    const float* inf_w = layer ? infw2 : infw1;
    const float* cls_b = layer ? clsb2 : clsb1;
    float* padd = layer ? padd2 : padd1;
    float prod = 1.0f;
#pragma unroll
    for (int d = 0; d < DEPTH; ++d) {
      const float* row = inf_w + ((size_t)d * DD + j) * DD;
      prod *= cosf(row[0]) * cosf(row[1]) * cosf(row[2]);
    }
    padd[j] = cls_b[j] + prod * prod * (1.0f / (float)DD);
  }
}

// ---------------- GEMM ----------------

__device__ __forceinline__ void gload_lds16(const unsigned short* g,
                                            unsigned short* l) {
  __builtin_amdgcn_global_load_lds(
      (const __attribute__((address_space(1))) void*)g,
      (__attribute__((address_space(3))) void*)l, 16, 0, 0);
}

#define MFMA_(A_, B_, C_) \
  __builtin_amdgcn_mfma_f32_16x16x32_bf16(A_, B_, C_, 0, 0, 0)

// Load B fragments for `tileexpr` into register set S (literal 0/1/2).
// Per lane: 4 x 16B from rows (nt*16 + lr), k-offset tile*BK + lg*8.
#define BLOAD(S, tileexpr) do {                                            \
    const unsigned short* _bp = Blane + (size_t)(tileexpr) * BK;           \
    _Pragma("unroll")                                                      \
    for (int _nt = 0; _nt < 4; ++_nt)                                      \
      breg##S[_nt] = *reinterpret_cast<const short8*>(                     \
          _bp + (size_t)(_nt * 16) * DD);                                  \
  } while (0)

// One pipeline step: wait (counted), barrier, B-prefetch(t+2), compute(t),
// stage A(t+3). BUF/S/LS are literals; WC selects vmcnt; DO_B/DO_A literal.
#define STEP(BUF, S, LS, t, WC, DO_B, DO_A) do {                           \
    if ((WC) == 0) asm volatile("s_waitcnt vmcnt(8)" ::: "memory");        \
    else if ((WC) == 1) asm volatile("s_waitcnt vmcnt(6)" ::: "memory");   \
    else asm volatile("s_waitcnt vmcnt(0)" ::: "memory");                  \
    __builtin_amdgcn_s_barrier();                                          \
    __builtin_amdgcn_sched_barrier(0);                                     \
    if (DO_B) BLOAD(LS, (t) + 2);                                          \
    {                                                                      \
      short8 _a0 = *reinterpret_cast<const short8*>(&As[(BUF)*ABUF + aoff0]); \
      short8 _a1 = *reinterpret_cast<const short8*>(&As[(BUF)*ABUF + aoff1]); \
      __builtin_amdgcn_s_setprio(1);                                       \
      _Pragma("unroll")                                                    \
      for (int _nt = 0; _nt < 4; ++_nt) {                                  \
        acc[0][_nt] = MFMA_(_a0, breg##S[_nt], acc[0][_nt]);               \
        acc[1][_nt] = MFMA_(_a1, breg##S[_nt], acc[1][_nt]);               \
      }                                                                    \
      __builtin_amdgcn_s_setprio(0);                                       \
    }                                                                      \
    __builtin_amdgcn_sched_barrier(0);                                     \
    if (DO_A) stageA(((BUF) + 3) & 3, (t) + 3);                            \
  } while (0)

// EPI: 0 = relu -> bf16, 1 = tanh -> bf16, 2 = relu -> f32
// A: [M][K] bf16 row-major. Bt: [N][K] bf16 (transposed weight). bias: [N].
// tsrc/tdst: optional weight transpose tail (for a LATER gemm's weight).
template <int EPI>
__global__ __launch_bounds__(256) void gemm_kernel(
    const unsigned short* __restrict__ A, const unsigned short* __restrict__ Bt,
    const float* __restrict__ bias, unsigned short* __restrict__ Cb,
    float* __restrict__ Cf, const float* __restrict__ tsrc,
    unsigned short* __restrict__ tdst) {
  const int N = DD, K = DD;
  // 36KB union: 4 A pipeline buffers (32KB) / epilogue f32 tile
  // (128*68*4 = 34816B) / tail transpose tile (64*65*4 = 16.6KB).
  __shared__ __align__(16) unsigned char smem[36864];
  unsigned short* As = (unsigned short*)smem;   // 4 x 4096 elements

  int tid = threadIdx.x;
  int wid = tid >> 6, lane = tid & 63;
  int lr = lane & 15;
  int lg = lane >> 4;

  // XCD-aware bijective swizzle over 512 blocks (512 % 8 == 0).
  int bid = blockIdx.x;
  int swz = (bid & 7) * 64 + (bid >> 3);
  int bcol = (swz & 31) * BN;   // 32 n-tiles
  int brow = (swz >> 5) * BM;   // 16 m-tiles

  const unsigned short* Abase = A + (size_t)brow * K;
  // per-lane B pointer: row (bcol + lr), k-offset lg*8; nt adds 16 rows.
  const unsigned short* Blane = Bt + (size_t)(bcol + lr) * DD + lg * 8;

  // A staging (rule 21): LDS dest linear; source slot pre-swizzled with the
  // reader's involution slot' = slot ^ ((row>>1)&3). 2 gload_lds/thread.
  auto stageA = [&](int buf, int tile) {
    int kt = tile * BK;
#pragma unroll
    for (int r = 0; r < 2; ++r) {
      int chunk = r * 256 + tid;          // 0..511 (A: 128 rows x 4 slots)
      int row = chunk >> 2;
      int sp = chunk & 3;
      int kof = (sp ^ ((row >> 1) & 3)) * 8;
      gload_lds16(Abase + (size_t)row * K + kt + kof,
                  As + buf * ABUF + (size_t)(r * 256 + wid * 64) * 8);
    }
  };

  // A-fragment LDS offsets (this wave owns rows [wid*32, wid*32+32)).
  int row0 = wid * 32 + lr;
  int row1 = row0 + 16;
  int aoff0 = row0 * BK + (lg ^ ((row0 >> 1) & 3)) * 8;
  int aoff1 = row1 * BK + (lg ^ ((row1 >> 1) & 3)) * 8;

  f32x4 acc[2][4];
#pragma unroll
  for (int i = 0; i < 2; ++i)
#pragma unroll
    for (int j = 0; j < 4; ++j) acc[i][j] = f32x4{0.f, 0.f, 0.f, 0.f};

  short8 breg0[4], breg1[4], breg2[4];   // 3 sets, tile t -> set t%3

  // Prologue (issue order A0 B0 A1 B1 A2 -> uniform vmcnt(8) from step 0).
  stageA(0, 0);
  BLOAD(0, 0);
  stageA(1, 1);
  BLOAD(1, 1);
  stageA(2, 2);

  // Main loop: steps 0..59, unroll 12 (A bufs mod 4, B sets mod 3).
#pragma unroll 1
  for (int i = 0; i < 5; ++i) {
    int t = 12 * i;
    STEP(0, 0, 2, t + 0, 0, 1, 1);
    STEP(1, 1, 0, t + 1, 0, 1, 1);
    STEP(2, 2, 1, t + 2, 0, 1, 1);
    STEP(3, 0, 2, t + 3, 0, 1, 1);
    STEP(0, 1, 0, t + 4, 0, 1, 1);
    STEP(1, 2, 1, t + 5, 0, 1, 1);
    STEP(2, 0, 2, t + 6, 0, 1, 1);
    STEP(3, 1, 0, t + 7, 0, 1, 1);
    STEP(0, 2, 1, t + 8, 0, 1, 1);
    STEP(1, 0, 2, t + 9, 0, 1, 1);
    STEP(2, 1, 0, t + 10, 0, 1, 1);
    STEP(3, 2, 1, t + 11, 0, 1, 1);
  }
  // Tail: steps 60..63.
  STEP(0, 0, 2, 60, 0, 1, 1);   // bload 62, stage 63
  STEP(1, 1, 0, 61, 0, 1, 0);   // bload 63
  STEP(2, 2, 1, 62, 1, 0, 0);   // vmcnt(6)
  STEP(3, 0, 2, 63, 2, 0, 0);   // vmcnt(0)

  // ---- epilogue: LDS-repack to coalesced 16B stores.
  // C/D layout col=lane&15, row=(lane>>4)*4+reg [m89-verified].
  {
    float* et = reinterpret_cast<float*>(smem);   // [128][68] f32
    __syncthreads();                              // pipeline LDS dead now
#pragma unroll
    for (int nt = 0; nt < 4; ++nt) {
      int colb = nt * 16 + lr;
      float bs = bias[bcol + colb];
#pragma unroll
      for (int mt = 0; mt < 2; ++mt) {
#pragma unroll
        for (int i = 0; i < 4; ++i) {
          int rowb = wid * 32 + mt * 16 + lg * 4 + i;
          float v = acc[mt][nt][i] + bs;
          v = (EPI == 1) ? tanhf(v) : fmaxf(v, 0.0f);
          et[rowb * 68 + colb] = v;
        }
      }
    }
    __syncthreads();
#pragma unroll
    for (int it = 0; it < 4; ++it) {
      int chunk = it * 256 + tid;          // 1024 chunks of 8 elements
      int rowb = chunk >> 3;
      int c8 = (chunk & 7) * 8;
      float4 v0 = *reinterpret_cast<const float4*>(&et[rowb * 68 + c8]);
      float4 v1 = *reinterpret_cast<const float4*>(&et[rowb * 68 + c8 + 4]);
      size_t g = (size_t)(brow + rowb) * N + bcol + c8;
      if (EPI == 2) {
        *reinterpret_cast<float4*>(&Cf[g]) = v0;
        *reinterpret_cast<float4*>(&Cf[g + 4]) = v1;
      } else {
        uint4 o;
        o.x = (unsigned)f2bf(v0.x) | ((unsigned)f2bf(v0.y) << 16);
        o.y = (unsigned)f2bf(v0.z) | ((unsigned)f2bf(v0.w) << 16);
        o.z = (unsigned)f2bf(v1.x) | ((unsigned)f2bf(v1.y) << 16);
        o.w = (unsigned)f2bf(v1.z) | ((unsigned)f2bf(v1.w) << 16);
        *reinterpret_cast<uint4*>(&Cb[g]) = o;
      }
    }
  }

  // ---- transpose tail: tdst[n*D+k] = bf16(tsrc[k*D+n]) for a later GEMM.
  // 1024 64x64 tiles over 512 blocks = 2 tiles/block.
  if (tsrc != nullptr) {
    float* ft = reinterpret_cast<float*>(smem);  // 64*65 f32 = 16.6KB
    __syncthreads();
#pragma unroll 1
    for (int t2 = 0; t2 < 2; ++t2) {
      int tau = bid * 2 + t2;
      int bx = (tau & 31) * 64;   // n base
      int by = (tau >> 5) * 64;   // k base
      if (t2) __syncthreads();
#pragma unroll
      for (int it = 0; it < 4; ++it) {
        int idx = it * 256 + tid;
        int r = idx >> 4, c4 = (idx & 15) * 4;
        float4 v = *reinterpret_cast<const float4*>(
            &tsrc[(size_t)(by + r) * DD + bx + c4]);
        ft[r * 65 + c4 + 0] = v.x;
        ft[r * 65 + c4 + 1] = v.y;
        ft[r * 65 + c4 + 2] = v.z;
        ft[r * 65 + c4 + 3] = v.w;
      }
      __syncthreads();
#pragma unroll
      for (int it = 0; it < 4; ++it) {
        int idx = it * 256 + tid;
        int n = idx >> 4, kq = idx & 15;
        ushort4 o;
        o.x = f2bf(ft[(kq * 4 + 0) * 65 + n]);
        o.y = f2bf(ft[(kq * 4 + 1) * 65 + n]);
        o.z = f2bf(ft[(kq * 4 + 2) * 65 + n]);
        o.w = f2bf(ft[(kq * 4 + 3) * 65 + n]);
        *reinterpret_cast<ushort4*>(&tdst[(size_t)(bx + n) * DD + by + kq * 4]) = o;
      }
    }
  }
}

// ---------------- launch ----------------

extern "C" void kernel_launch(void* const* d_in, const int* in_sizes, int n_in,
                              void* d_out, int out_size, void* d_ws,
                              size_t ws_size, hipStream_t stream) {
  const float* x     = (const float*)d_in[0];
  const float* w0    = (const float*)d_in[1];
  const float* b0    = (const float*)d_in[2];
  const float* w1    = (const float*)d_in[3];
  const float* b1    = (const float*)d_in[4];
  const float* infw1 = (const float*)d_in[5];
  const float* clsw1 = (const float*)d_in[6];
  const float* clsb1 = (const float*)d_in[7];
  const float* w2    = (const float*)d_in[8];
  const float* b2    = (const float*)d_in[9];
  const float* infw2 = (const float*)d_in[10];
  const float* clsw2 = (const float*)d_in[11];
  const float* clsb2 = (const float*)d_in[12];
  const float* w3    = (const float*)d_in[13];
  const float* b3    = (const float*)d_in[14];
  float* out = (float*)d_out;

  char* ws = (char*)d_ws;
  const size_t MB = 1ull << 20;
  const size_t DDe = (size_t)DD * DD;
  unsigned short* buf0 = (unsigned short*)ws;              // 8 MB (x_bf16 / act)
  unsigned short* buf1 = (unsigned short*)(ws + 8 * MB);   // 8 MB (act)
  unsigned short* wts  = (unsigned short*)(ws + 16 * MB);  // 6 x 8 MB
  float* padd1 = (float*)(ws + 64 * MB);
  float* padd2 = padd1 + DD;

  prep_kernel<<<12304, 256, 0, stream>>>(w0, w1, wts, x, buf0, infw1, infw2,
                                         clsb1, clsb2, padd1, padd2);

  dim3 gg((DD / BM) * (DD / BN));  // 512 blocks -> 2 blocks/CU
  // GEMM_i tail-transposes the weight consumed by GEMM_{i+2} (stream order
  // guarantees GEMM_i completes before GEMM_{i+1} starts).
  gemm_kernel<0><<<gg, 256, 0, stream>>>(buf0, wts + 0 * DDe, b0,    buf1,
                                         nullptr, clsw1, wts + 2 * DDe);
  gemm_kernel<0><<<gg, 256, 0, stream>>>(buf1, wts + 1 * DDe, b1,    buf0,
                                         nullptr, w2,    wts + 3 * DDe);
  gemm_kernel<1><<<gg, 256, 0, stream>>>(buf0, wts + 2 * DDe, padd1, buf1,
                                         nullptr, clsw2, wts + 4 * DDe);
  gemm_kernel<0><<<gg, 256, 0, stream>>>(buf1, wts + 3 * DDe, b2,    buf0,
                                         nullptr, w3,    wts + 5 * DDe);
  gemm_kernel<1><<<gg, 256, 0, stream>>>(buf0, wts + 4 * DDe, padd2, buf1,
                                         nullptr, nullptr, nullptr);
  gemm_kernel<2><<<gg, 256, 0, stream>>>(buf1, wts + 5 * DDe, b3,    nullptr,
                                         out, nullptr, nullptr);
}